// Round 5
// baseline (1259.746 us; speedup 1.0000x reference)
//
#include <hip/hip_runtime.h>
#include <hip/hip_fp16.h>
#include <stdint.h>
#include <math.h>

#define HWS 16384
#define NPIX (16 * HWS)
#define T 128

// float offsets into d_ws. All weight matrices stored TRANSPOSED: [cin][out],
// so c-outer/o-inner accumulation reads contiguous runs of `out` floats.
enum {
  OFF_W1  = 0,      // [48][24] rb conv1 (bn-folded)
  OFF_B1  = 1152,   // 24
  OFF_W2  = 1176,   // [24][48] rb conv2 (post-residual bn folded)
  OFF_B2  = 2328,   // 48
  OFF_XS  = 2376,   // 48  bn scale applied to xs in residual add
  OFF_WQ  = 2424,   // [48][48]
  OFF_BQ  = 4728,   // 48
  OFF_WV  = 4776,   // [48][48]
  OFF_BV  = 7080,   // 48
  OFF_WK1 = 7128,   // [48][24]
  OFF_BK1 = 8280,   // 24
  OFF_WK2 = 8304,   // [48][24]
  OFF_BK2 = 9456,   // 24
  OFF_WCF = 9480,   // [96][48]
  OFF_BCF = 14088,  // 48
  OFF_WE1 = 14136,  // [48][24] emb conv1 (no bn)
  OFF_BE1 = 15288,  // 24
  OFF_WE2 = 15312,  // [24][48]
  OFF_BE2 = 16464,  // 48
  WS_TOTAL = 16512
};

struct PtrPack { const float* p[48]; };

// bn fold: s = g/sqrt(v+eps), t = beta - m*s;  bn(conv(x,W,b)) = (s.W)x + (s.b + t)
#define SCALE_T(bnb, o, s, t)                                       \
  {                                                                 \
    float g_ = P.p[(bnb)][(o)], be_ = P.p[(bnb) + 1][(o)];          \
    float m_ = P.p[(bnb) + 2][(o)], v_ = P.p[(bnb) + 3][(o)];       \
    s = g_ / sqrtf(v_ + 1e-5f);                                     \
    t = be_ - m_ * s;                                               \
  }

__global__ void fold_kernel(PtrPack P, float* __restrict__ W) {
  int i = blockIdx.x * blockDim.x + threadIdx.x;
  float s, t;
  if (i < OFF_B1)        { int j = i;            int ci = j / 24, o = j % 24; SCALE_T(4,  o, s, t); W[i] = s * P.p[2][o * 48 + ci]; }
  else if (i < OFF_W2)   { int o = i - OFF_B1;                                SCALE_T(4,  o, s, t); W[i] = s * P.p[3][o] + t; }
  else if (i < OFF_B2)   { int j = i - OFF_W2;   int ci = j / 48, o = j % 48; SCALE_T(10, o, s, t); W[i] = s * P.p[8][o * 24 + ci]; }
  else if (i < OFF_XS)   { int o = i - OFF_B2;                                SCALE_T(10, o, s, t); W[i] = s * P.p[9][o] + t; }
  else if (i < OFF_WQ)   { int o = i - OFF_XS;                                SCALE_T(10, o, s, t); W[i] = s; }
  else if (i < OFF_BQ)   { int j = i - OFF_WQ;   int ci = j / 48, o = j % 48; SCALE_T(16, o, s, t); W[i] = s * P.p[14][o * 48 + ci]; }
  else if (i < OFF_WV)   { int o = i - OFF_BQ;                                SCALE_T(16, o, s, t); W[i] = s * P.p[15][o] + t; }
  else if (i < OFF_BV)   { int j = i - OFF_WV;   int ci = j / 48, o = j % 48; SCALE_T(22, o, s, t); W[i] = s * P.p[20][o * 48 + ci]; }
  else if (i < OFF_WK1)  { int o = i - OFF_BV;                                SCALE_T(22, o, s, t); W[i] = s * P.p[21][o] + t; }
  else if (i < OFF_BK1)  { int j = i - OFF_WK1;  int ci = j / 24, o = j % 24; SCALE_T(28, o, s, t); W[i] = s * P.p[26][o * 48 + ci]; }
  else if (i < OFF_WK2)  { int o = i - OFF_BK1;                               SCALE_T(28, o, s, t); W[i] = s * P.p[27][o] + t; }
  else if (i < OFF_BK2)  { int j = i - OFF_WK2;  int ci = j / 24, o = j % 24; SCALE_T(34, o, s, t); W[i] = s * P.p[32][o * 48 + ci]; }
  else if (i < OFF_WCF)  { int o = i - OFF_BK2;                               SCALE_T(34, o, s, t); W[i] = s * P.p[33][o] + t; }
  else if (i < OFF_BCF)  { int j = i - OFF_WCF;  int ci = j / 48, o = j % 48; SCALE_T(40, o, s, t); W[i] = s * P.p[38][o * 96 + ci]; }
  else if (i < OFF_WE1)  { int o = i - OFF_BCF;                               SCALE_T(40, o, s, t); W[i] = s * P.p[39][o] + t; }
  else if (i < OFF_BE1)  { int j = i - OFF_WE1;  int ci = j / 24, o = j % 24; W[i] = P.p[44][o * 48 + ci]; }
  else if (i < OFF_WE2)  { int o = i - OFF_BE1;  W[i] = P.p[45][o]; }
  else if (i < OFF_BE2)  { int j = i - OFF_WE2;  int ci = j / 48, o = j % 48; W[i] = P.p[46][o * 24 + ci]; }
  else if (i < WS_TOTAL) { int o = i - OFF_BE2;  W[i] = P.p[47][o]; }
}

// ---------------- fused per-pixel forward, X-state in LDS as fp16 pairs ----------------

__device__ __forceinline__ float gelu_f(float x) {
  return 0.5f * x * (1.f + erff(x * 0.70710678118654752440f));
}

__global__ __attribute__((amdgpu_waves_per_eu(3))) __launch_bounds__(T)
void fused_main(const float* __restrict__ x0g,
                const float* __restrict__ x1g,
                const float* __restrict__ W,
                float* __restrict__ out) {
  // Per-thread private column of channel-pairs; [cp][tid] layout ->
  // lane-consecutive addresses, conflict-free, no cross-thread sharing.
  __shared__ __half2 Xh[2][24][T];
  const int tid = threadIdx.x;
  const int p = blockIdx.x * T + tid;
  const int b = p >> 14;  // hw = 16384
  const int n = p & (HWS - 1);

  {
    const float* px0 = x0g + (size_t)b * 48 * HWS + n;
    const float* px1 = x1g + (size_t)b * 48 * HWS + n;
#pragma unroll 4
    for (int cp = 0; cp < 24; cp++) {
      Xh[0][cp][tid] = __floats2half2_rn(px0[(size_t)(2 * cp) * HWS], px0[(size_t)(2 * cp + 1) * HWS]);
      Xh[1][cp][tid] = __floats2half2_rn(px1[(size_t)(2 * cp) * HWS], px1[(size_t)(2 * cp + 1) * HWS]);
    }
  }

  float la[48];

#pragma unroll 1
  for (int k = 0; k < 4; k++) {
    // ---- residual blocks (in-place on Xh), c-outer accumulation ----
#pragma unroll 1
    for (int s = 0; s < 2; s++) {
      float r[24];
#pragma unroll
      for (int o = 0; o < 24; o++) r[o] = W[OFF_B1 + o];
#pragma unroll 2
      for (int cp = 0; cp < 24; cp++) {
        __half2 u = Xh[s][cp][tid];
        float x0c = __low2float(u), x1c = __high2float(u);
#pragma unroll
        for (int o = 0; o < 24; o++) {
          r[o] = fmaf(W[OFF_W1 + (2 * cp) * 24 + o], x0c, r[o]);
          r[o] = fmaf(W[OFF_W1 + (2 * cp + 1) * 24 + o], x1c, r[o]);
        }
      }
#pragma unroll
      for (int o = 0; o < 24; o++) r[o] = fmaxf(r[o], 0.f);

      float acc[48];
#pragma unroll
      for (int o = 0; o < 48; o++) acc[o] = W[OFF_B2 + o];
#pragma unroll 2
      for (int c = 0; c < 24; c++) {
#pragma unroll
        for (int o = 0; o < 48; o++) acc[o] = fmaf(W[OFF_W2 + c * 48 + o], r[c], acc[o]);
      }
#pragma unroll
      for (int op = 0; op < 24; op++) {
        __half2 u = Xh[s][op][tid];
        float xo0 = __low2float(u), xo1 = __high2float(u);
        float n0 = fmaxf(fmaf(W[OFF_XS + 2 * op], xo0, acc[2 * op]), 0.f);
        float n1 = fmaxf(fmaf(W[OFF_XS + 2 * op + 1], xo1, acc[2 * op + 1]), 0.f);
        Xh[s][op][tid] = __floats2half2_rn(n0, n1);
      }
    }

    // ---- k==0: la = emb(relu(cf @ concat(X0,X1))) ----
    if (k == 0) {
      float tv[48];
#pragma unroll
      for (int o = 0; o < 48; o++) tv[o] = W[OFF_BCF + o];
#pragma unroll 1
      for (int s = 0; s < 2; s++) {
#pragma unroll 2
        for (int cp = 0; cp < 24; cp++) {
          __half2 u = Xh[s][cp][tid];
          float x0c = __low2float(u), x1c = __high2float(u);
#pragma unroll
          for (int o = 0; o < 48; o++) {
            tv[o] = fmaf(W[OFF_WCF + (s * 48 + 2 * cp) * 48 + o], x0c, tv[o]);
            tv[o] = fmaf(W[OFF_WCF + (s * 48 + 2 * cp + 1) * 48 + o], x1c, tv[o]);
          }
        }
      }
#pragma unroll
      for (int o = 0; o < 48; o++) tv[o] = fmaxf(tv[o], 0.f);

      float h[24];
#pragma unroll
      for (int o = 0; o < 24; o++) h[o] = W[OFF_BE1 + o];
#pragma unroll 2
      for (int c = 0; c < 48; c++) {
#pragma unroll
        for (int o = 0; o < 24; o++) h[o] = fmaf(W[OFF_WE1 + c * 24 + o], tv[c], h[o]);
      }
#pragma unroll
      for (int o = 0; o < 24; o++) h[o] = gelu_f(h[o]);
#pragma unroll
      for (int o = 0; o < 48; o++) la[o] = W[OFF_BE2 + o];
#pragma unroll 2
      for (int c = 0; c < 24; c++) {
#pragma unroll
        for (int o = 0; o < 48; o++) la[o] = fmaf(W[OFF_WE2 + c * 48 + o], h[c], la[o]);
      }
    }

    // ---- kk1, kk2 from la (la dead afterwards) ----
    float kk1[24], kk2[24];
#pragma unroll
    for (int o = 0; o < 24; o++) { kk1[o] = W[OFF_BK1 + o]; kk2[o] = W[OFF_BK2 + o]; }
#pragma unroll 2
    for (int c = 0; c < 48; c++) {
      float lc = la[c];
#pragma unroll
      for (int o = 0; o < 24; o++) {
        kk1[o] = fmaf(W[OFF_WK1 + c * 24 + o], lc, kk1[o]);
        kk2[o] = fmaf(W[OFF_WK2 + c * 24 + o], lc, kk2[o]);
      }
    }

    // ---- scores: m order = {x0 lo, x0 hi, x1 lo, x1 hi} ----
    float s1[4], s2[4];
#pragma unroll
    for (int s = 0; s < 2; s++) {
      float q[48];
#pragma unroll
      for (int o = 0; o < 48; o++) q[o] = W[OFF_BQ + o];
#pragma unroll 2
      for (int cp = 0; cp < 24; cp++) {
        __half2 u = Xh[s][cp][tid];
        float x0c = __low2float(u), x1c = __high2float(u);
#pragma unroll
        for (int o = 0; o < 48; o++) {
          q[o] = fmaf(W[OFF_WQ + (2 * cp) * 48 + o], x0c, q[o]);
          q[o] = fmaf(W[OFF_WQ + (2 * cp + 1) * 48 + o], x1c, q[o]);
        }
      }
      float a10 = 0.f, a11 = 0.f, a20 = 0.f, a21 = 0.f;
#pragma unroll
      for (int o = 0; o < 24; o++) {
        a10 = fmaf(kk1[o], q[o], a10);
        a20 = fmaf(kk2[o], q[o], a20);
        a11 = fmaf(kk1[o], q[24 + o], a11);
        a21 = fmaf(kk2[o], q[24 + o], a21);
      }
      s1[2 * s] = a10; s1[2 * s + 1] = a11;
      s2[2 * s] = a20; s2[2 * s + 1] = a21;
    }
    // softmax over the 4 scores (per pixel)
    {
      float m1 = fmaxf(fmaxf(s1[0], s1[1]), fmaxf(s1[2], s1[3]));
      float e0 = __expf(s1[0] - m1), e1 = __expf(s1[1] - m1), e2 = __expf(s1[2] - m1), e3 = __expf(s1[3] - m1);
      float inv = 1.f / (e0 + e1 + e2 + e3);
      s1[0] = e0 * inv; s1[1] = e1 * inv; s1[2] = e2 * inv; s1[3] = e3 * inv;
      float m2 = fmaxf(fmaxf(s2[0], s2[1]), fmaxf(s2[2], s2[3]));
      float f0 = __expf(s2[0] - m2), f1 = __expf(s2[1] - m2), f2 = __expf(s2[2] - m2), f3 = __expf(s2[3] - m2);
      float jnv = 1.f / (f0 + f1 + f2 + f3);
      s2[0] = f0 * jnv; s2[1] = f1 * jnv; s2[2] = f2 * jnv; s2[3] = f3 * jnv;
    }

    // ---- values: r_j[c] = sum_m att_j[m] * v_m[c] ----
    float r1[24], r2[24];
#pragma unroll
    for (int o = 0; o < 24; o++) { r1[o] = 0.f; r2[o] = 0.f; }
#pragma unroll
    for (int s = 0; s < 2; s++) {
      float v[48];
#pragma unroll
      for (int o = 0; o < 48; o++) v[o] = W[OFF_BV + o];
#pragma unroll 2
      for (int cp = 0; cp < 24; cp++) {
        __half2 u = Xh[s][cp][tid];
        float x0c = __low2float(u), x1c = __high2float(u);
#pragma unroll
        for (int o = 0; o < 48; o++) {
          v[o] = fmaf(W[OFF_WV + (2 * cp) * 48 + o], x0c, v[o]);
          v[o] = fmaf(W[OFF_WV + (2 * cp + 1) * 48 + o], x1c, v[o]);
        }
      }
#pragma unroll
      for (int o = 0; o < 24; o++) {
        r1[o] = fmaf(s1[2 * s], v[o], r1[o]);
        r1[o] = fmaf(s1[2 * s + 1], v[24 + o], r1[o]);
        r2[o] = fmaf(s2[2 * s], v[o], r2[o]);
        r2[o] = fmaf(s2[2 * s + 1], v[24 + o], r2[o]);
      }
    }

    // ---- la = emb(concat(r1, r2)) ----
    {
      float h[24];
#pragma unroll
      for (int o = 0; o < 24; o++) h[o] = W[OFF_BE1 + o];
#pragma unroll 2
      for (int c = 0; c < 24; c++) {
#pragma unroll
        for (int o = 0; o < 24; o++) {
          h[o] = fmaf(W[OFF_WE1 + c * 24 + o], r1[c], h[o]);
          h[o] = fmaf(W[OFF_WE1 + (24 + c) * 24 + o], r2[c], h[o]);
        }
      }
#pragma unroll
      for (int o = 0; o < 24; o++) h[o] = gelu_f(h[o]);
#pragma unroll
      for (int o = 0; o < 48; o++) la[o] = W[OFF_BE2 + o];
#pragma unroll 2
      for (int c = 0; c < 24; c++) {
#pragma unroll
        for (int o = 0; o < 48; o++) la[o] = fmaf(W[OFF_WE2 + c * 48 + o], h[c], la[o]);
      }
    }
  }

  float* po = out + (size_t)b * 48 * HWS + n;
#pragma unroll 4
  for (int c = 0; c < 48; c++) po[(size_t)c * HWS] = la[c];
}

extern "C" void kernel_launch(void* const* d_in, const int* in_sizes, int n_in,
                              void* d_out, int out_size, void* d_ws, size_t ws_size,
                              hipStream_t stream) {
  PtrPack P;
  for (int i = 0; i < 48; i++) P.p[i] = (const float*)d_in[i];
  float* W = (float*)d_ws;

  fold_kernel<<<(WS_TOTAL + 255) / 256, 256, 0, stream>>>(P, W);
  fused_main<<<NPIX / T, T, 0, stream>>>(P.p[0], P.p[1], W, (float*)d_out);
}